// Round 1
// 138.904 us; speedup vs baseline: 1.0071x; 1.0071x over previous
//
#include <hip/hip_runtime.h>

// Problem constants
#define BB 4
#define CC 32
#define LL 50176              // 224*224
#define KK2 25
#define CDTOT (BB * LL * KK2) // 5,017,600 floats in cd

// out[b,c2,l2] = in[b,c2,l2] * sum_k2 Wt(b,l2,k2) * V(b,n).
// Lanes stride l2 by 800 (l2 = rem + 800*ii, rem wave-uniform).
// KEY IDENTITY: ys*224 + xs = u  =>  unclamped gather addr
//     addr = A0(k2) + ii + 1568*c2,  A0 = c*LL + 224*dy + dx + e0  (WAVE-UNIFORM)
// x-OOB lanes read +-2 off (in-bounds within batch slab) but weight=0.
// => load is uniform_base[ii]: saddr form, 1 VALU + 1 load per MAC, A-table in SGPRs.
// Interior c2 in [1,30] always y-in-bounds; c2=0/31 via clamped special pass.
// Stores PLAIN (R5: nontemporal stores defeated write-combining 25->97MB).
// 8 channels per exchange group -> 200 loads in flight, 2 barriers.
// R6: cd staging via global_load_lds (direct HBM->LDS DMA, no VGPR round-trip,
//     no intermediate waitcnts; single drain at the existing barrier). Width=4
//     keeps the stride-101 padded layout -> setup reads stay conflict-free.

typedef const float __attribute__((address_space(1)))* gcd_ptr;
typedef float __attribute__((address_space(3)))* lds_ptr;

__global__ __launch_bounds__(256) void conv_local_kernel(
    const float* __restrict__ input,
    const float* __restrict__ cd,
    const float* __restrict__ colw,
    const float* __restrict__ posw,
    float* __restrict__ out)
{
    // 6656 floats: staging writes slots [0,6656) (64 rows x 101 + DMA overshoot),
    // rows use 100 of 101 (pad slot = junk). Exchange reuses [0,5120) afterwards.
    __shared__ float smem[6656];

    const int t    = threadIdx.x;
    const int lane = t & 63;
    const int w    = t >> 6;              // wave 0..3 -> rem = rem0 + w

    // XCD-locality swizzle (validated R3: FETCH 211->42MB)
    const int bx   = blockIdx.x;          // 0..1599
    const int xcd  = bx & 7;
    const int slot = bx >> 3;             // 0..199
    const int b    = xcd >> 1;            // batch pinned to XCD pair
    const int j    = slot * 2 + (xcd & 1);// 0..399 within batch
    const int chunk  = j & 1;             // c2-chunk: [0,16) or [16,32)
    const int rem0   = (j >> 1) * 4;      // 0..796
    const int c2base = chunk * 16;

    const float cw = colw[0];
    const float pw = posw[0];
    const float* __restrict__ in_b  = input + b * (CC * LL);
    float* __restrict__       out_b = out   + b * (CC * LL);

    // ---- stage cd for this block's 256 l2 values: direct global->LDS DMA ----
    // Slot s = ci*101 + pos; pos==100 is the pad slot (loads clamped junk, unused).
    // Each issue: 64 consecutive slots per wave, LDS dest = uniform base + lane*4.
    {
        const int cd_base = b * (LL * KK2);
        #pragma unroll
        for (int jj = 0; jj < 26; ++jj) {
            int s    = t + 256 * jj;             // slot in [0, 6656)
            int ci   = s / 101;                  // row 0..65 (>=64 -> junk, clamped)
            int pos  = s - ci * 101;             // (rem-rem0)*25 + k2, or 100 = pad
            int gidx = cd_base + (rem0 + 800 * ci) * KK2 + pos;
            gidx = min(gidx, CDTOT - 1);         // clamp pad/OOB (values unused)
            __builtin_amdgcn_global_load_lds((gcd_ptr)(cd + gidx),
                                             (lds_ptr)(smem + (jj * 256 + w * 64)),
                                             4, 0, 0);
        }
    }
    __syncthreads();   // drains vmcnt -> staged cd visible

    // ---- per-thread setup ----
    const int remU = __builtin_amdgcn_readfirstlane(rem0 + w);  // wave-uniform
    const int ii   = lane;

    float Wt[KK2];   // per-lane weight, x-mask folded in (fp32)
    int   A0u[KK2];  // WAVE-UNIFORM base: c*LL + 224*dy + dx + e0  (-> SGPRs)
    const float POS[KK2] = {8,5,4,5,8, 5,2,1,2,5, 4,1,0,1,4, 5,2,1,2,5, 8,5,4,5,8};

    #pragma unroll
    for (int k2 = 0; k2 < KK2; ++k2) {
        int t1 = 576 * k2 + remU;       // all scalar:
        int q0 = t1 / 800;
        int r  = t1 - q0 * 800;
        int c  = r / 25;
        int s  = r - c * 25;
        int dy = s / 5 - 2;
        int dx = s % 5 - 2;
        int e0 = 62 * k2 + q0;          // <= 1506
        A0u[k2] = c * LL + 224 * dy + dx + e0;
        int u  = e0 + ii;               // vector: +lane
        int ys = u / 224;               // [0,7]
        int xs = u - ys * 224;
        int xm = xs + dx;
        bool xok = (unsigned)xm < 224u;
        float wgt = fmaf(smem[ii * 101 + w * 25 + k2], cw, POS[k2] * pw);
        Wt[k2] = xok ? wgt : 0.0f;      // x-mask folded into weight
    }
    __syncthreads();   // smem reused as exchange buffer from here

    // mapping B (contiguous-l2) constants for coalesced iv-load / store
    const int remB = t & 3;
    const int iiB  = t >> 2;
    const int l2B  = rem0 + remB + 800 * iiB;
    const bool okB = l2B < LL;
    const int idxB = min(l2B, LL - 1);

    // ---- main loop: 2 groups of 8 channels ----
    #pragma unroll 1
    for (int gg = 0; gg < 2; ++gg) {
        float acc[8], iv[8];
        #pragma unroll
        for (int g = 0; g < 8; ++g) {
            acc[g] = 0.0f;
            iv[g]  = in_b[(c2base + gg * 8 + g) * LL + idxB];  // coalesced, overlaps gathers
        }

        // interior gathers: uniform base + lane offset -> saddr loads
        #pragma unroll
        for (int k2 = 0; k2 < KK2; ++k2) {
            const float wv = Wt[k2];
            #pragma unroll
            for (int g = 0; g < 8; ++g) {
                int c2  = c2base + gg * 8 + g;
                int c2e = min(max(c2, 1), 30);   // special slots: dummy interior read
                const float* bp = in_b + (A0u[k2] + 1568 * c2e);  // wave-uniform ptr
                acc[g] = fmaf(bp[ii], wv, acc[g]);
            }
        }

        // special channels c2=0 / c2=31: clamped + y-masked pass, OVERWRITES acc
        const bool sp_here = (chunk == 0) ? (gg == 0) : (gg == 1);
        if (sp_here) {
            const bool sp0 = (chunk == 0);
            float a = 0.0f;
            #pragma unroll
            for (int k2 = 0; k2 < KK2; ++k2) {
                int t1 = 576 * k2 + remU;
                int q0 = t1 / 800;
                int r  = t1 - q0 * 800;
                int c  = r / 25;
                int s  = r - c * 25;
                int dy = s / 5 - 2;
                int dx = s % 5 - 2;
                int u  = 62 * k2 + q0 + ii;
                int ys = u / 224;
                int xs = u - ys * 224;
                int xc = min(max(xs + dx, 0), 223);
                int yy = ys + dy;                     // [-2, 9]
                int yb = sp0 ? max(yy, 0) : (217 + min(yy, 6));
                bool ok = sp0 ? (yy >= 0) : (yy <= 6);
                float v = in_b[c * LL + yb * 224 + xc];
                a = fmaf(ok ? v : 0.0f, Wt[k2], a);
            }
            if (sp0) acc[0] = a; else acc[7] = a;
        }

        // exchange to mapping B; strides 320/80 -> max 2-way LDS access (free)
        float* sbuf = smem + gg * 2560;
        #pragma unroll
        for (int g = 0; g < 8; ++g)
            sbuf[g * 320 + w * 80 + lane] = acc[g];
        __syncthreads();
        #pragma unroll
        for (int g = 0; g < 8; ++g) {
            float S = sbuf[g * 320 + remB * 80 + iiB];
            if (okB) out_b[(c2base + gg * 8 + g) * LL + idxB] = S * iv[g];  // plain store
        }
        // no trailing barrier: gg=1 uses a disjoint sbuf region
    }
}

extern "C" void kernel_launch(void* const* d_in, const int* in_sizes, int n_in,
                              void* d_out, int out_size, void* d_ws, size_t ws_size,
                              hipStream_t stream) {
    const float* input = (const float*)d_in[0];
    const float* cdist = (const float*)d_in[1];
    const float* cwp   = (const float*)d_in[2];
    const float* pwp   = (const float*)d_in[3];
    float* o = (float*)d_out;

    dim3 grid(1600);   // 4 b x 2 chunks x 200 rem0-tiles, XCD-pinned in-kernel
    dim3 block(256);
    hipLaunchKernelGGL(conv_local_kernel, grid, block, 0, stream,
                       input, cdist, cwp, pwp, o);
}